// Round 18
// baseline (124.795 us; speedup 1.0000x reference)
//
#include <hip/hip_runtime.h>
#include <hip/hip_bf16.h>
#include <stdint.h>

// ---------- types ----------
typedef __bf16 bf16x8 __attribute__((ext_vector_type(8)));
typedef __bf16 bf16x4 __attribute__((ext_vector_type(4)));
typedef float  f32x4  __attribute__((ext_vector_type(4)));

__device__ __forceinline__ unsigned short f2bf(float f) {
    unsigned u = __builtin_bit_cast(unsigned, f);
    u += 0x7fffu + ((u >> 16) & 1u);   // RNE
    return (unsigned short)(u >> 16);
}

__device__ __forceinline__ float bf2f(unsigned short u) {
    return __builtin_bit_cast(float, (unsigned)u << 16);
}

__device__ __forceinline__ void gload16(const void* g, void* l) {
    __builtin_amdgcn_global_load_lds((const __attribute__((address_space(1))) void*)g,
                                     (__attribute__((address_space(3))) void*)l, 16, 0, 0);
}

// ---------- fused fp32 -> bf16 convert for x, w_qkv, w_proj (one launch) ----------
#define XN  4194304   // 4096*1024
#define WQN 3145728   // 3072*1024
#define WPN 1048576   // 1024*1024
__global__ void cvt_all(const float* __restrict__ x, const float* __restrict__ wq,
                        const float* __restrict__ wp,
                        unsigned short* __restrict__ xb, unsigned short* __restrict__ wqb,
                        unsigned short* __restrict__ wpb) {
    int i = (blockIdx.x * blockDim.x + threadIdx.x) * 4;
    const float* src; unsigned short* dst; int off;
    if (i < XN)            { src = x;  dst = xb;  off = i; }
    else if (i < XN + WQN) { src = wq; dst = wqb; off = i - XN; }
    else                   { src = wp; dst = wpb; off = i - XN - WQN; }
    float4 v = *(const float4*)(src + off);
    ushort4 o;
    o.x = f2bf(v.x); o.y = f2bf(v.y); o.z = f2bf(v.z); o.w = f2bf(v.w);
    *(ushort4*)(dst + off) = o;
}

// ---------- GEMM C = A * B^T (proven 128x128 structure) ----------
#define BM 128
#define BN 128
#define BKK 64

template<int MODE>
__global__ void gemm_bt(const unsigned short* __restrict__ A,
                        const unsigned short* __restrict__ Bm,
                        int M, int N, int K,
                        float* __restrict__ Cf,
                        unsigned short* __restrict__ Qo,
                        unsigned short* __restrict__ Ko,
                        unsigned short* __restrict__ Vo) {
    __shared__ __align__(16) unsigned short Als[BM * BKK];
    __shared__ __align__(16) unsigned short Bls[BN * BKK];

    const int tid  = threadIdx.x;
    const int lane = tid & 63;
    const int wave = tid >> 6;
    const int wm = wave >> 1, wn = wave & 1;
    const int nwg = gridDim.x * gridDim.y;
    const int lid = blockIdx.y * gridDim.x + blockIdx.x;
    const int cpx = nwg >> 3;
    const int swz = (lid & 7) * cpx + (lid >> 3);
    const int m0 = (swz / gridDim.x) * BM, n0 = (swz % gridDim.x) * BN;
    const int l16 = lane & 15, lg = lane >> 4;

    f32x4 acc[4][4];
#pragma unroll
    for (int i = 0; i < 4; i++)
#pragma unroll
        for (int j = 0; j < 4; j++) acc[i][j] = f32x4{0.f, 0.f, 0.f, 0.f};

    const int r0 = tid >> 3;
    const int c8 = tid & 7;

    for (int k0 = 0; k0 < K; k0 += BKK) {
        __syncthreads();
#pragma unroll
        for (int i = 0; i < 4; i++) {
            gload16(A  + (size_t)(m0 + r0 + i * 32) * K + k0 + c8 * 8,
                    Als + i * 2048 + wave * 512);
            gload16(Bm + (size_t)(n0 + r0 + i * 32) * K + k0 + c8 * 8,
                    Bls + i * 2048 + wave * 512);
        }
        __syncthreads();
#pragma unroll
        for (int ks = 0; ks < 2; ++ks) {
            const int koff = ks * 32 + lg * 8;
            bf16x8 af[4], bfv[4];
#pragma unroll
            for (int mf = 0; mf < 4; ++mf)
                af[mf] = *(const bf16x8*)(Als + (wm * 64 + mf * 16 + l16) * BKK + koff);
#pragma unroll
            for (int nf = 0; nf < 4; ++nf)
                bfv[nf] = *(const bf16x8*)(Bls + (wn * 64 + nf * 16 + l16) * BKK + koff);
#pragma unroll
            for (int mf = 0; mf < 4; ++mf)
#pragma unroll
                for (int nf = 0; nf < 4; ++nf)
                    acc[mf][nf] = __builtin_amdgcn_mfma_f32_16x16x32_bf16(af[mf], bfv[nf], acc[mf][nf], 0, 0, 0);
        }
    }

#pragma unroll
    for (int mf = 0; mf < 4; ++mf) {
        int gm = m0 + wm * 64 + mf * 16 + (lg << 2);
#pragma unroll
        for (int nf = 0; nf < 4; ++nf) {
            int gn = n0 + wn * 64 + nf * 16 + l16;
            if (MODE == 0) {
                int which = gn >> 10;
                int rem = gn & 1023;
                int h = rem >> 6, d = rem & 63;
                unsigned short* dst = (which == 0) ? Qo : (which == 1) ? Ko : Vo;
                float s = (which == 0) ? 0.180336884f : 1.0f;   // 0.125 * log2(e) for Q
#pragma unroll
                for (int j = 0; j < 4; j++) {
                    int m = gm + j;
                    int b = m >> 11, t = m & 2047;
                    dst[((size_t)((b << 4) + h) * 2048 + t) * 64 + d] = f2bf(acc[mf][nf][j] * s);
                }
            } else {
#pragma unroll
                for (int j = 0; j < 4; j++)
                    Cf[(size_t)(gm + j) * N + gn] = acc[mf][nf][j];
            }
        }
    }
}

// ---------- causal flash attention with K-SPLIT (R7 pipeline, 2x TLP) ----------
// 1024 blocks. Decode hedged over BOTH plausible co-residency models:
//   u=(bid>>3)&3, s=(bid>>5)&3, v=(bid>>8)&3;
//   qt = QMAP[(u^v)*4 + s], half=(bid>>7)&1, bh = v*8 + (bid&7).
// Depth-first fill (co-resident quad {+8,+16,+24}: u varies) AND stride-256 striping
// (v varies) both see qt-selector vary; QMAP's aligned columns each sum to 30 ->
// every CU gets 34 tile-units under either model (vs 4..64 before). Bijective.
// Each half-block stores unnormalized O~ (bf16) + per-row (m,l); combine merges.
// NOTE (R15): no device-scope fence fusion — __threadfence() = L2 writeback (9x).
__global__ __launch_bounds__(512, 4)
void attn_split(const unsigned short* __restrict__ Q,
                const unsigned short* __restrict__ Kg,
                const unsigned short* __restrict__ V,
                unsigned short* __restrict__ O1,
                unsigned short* __restrict__ O2,
                float2* __restrict__ st1,
                float2* __restrict__ st2) {
    __shared__ __align__(16) unsigned short Kls[64 * 64];
    __shared__ __align__(16) unsigned short Vt[64 * 64];   // [dim][key], swizzled
    __shared__ __align__(16) unsigned short Pls[8][16 * 64];

    const int tid = threadIdx.x, lane = tid & 63, wv = tid >> 6;
    const int l16 = lane & 15, lg = lane >> 4;
    const int bid = blockIdx.x;
    const int u  = (bid >> 3) & 3, s5 = (bid >> 5) & 3, v5 = (bid >> 8) & 3;
    // QMAP = {15,14,13,12, 8,9,10,11, 4,5,6,7, 3,2,1,0} packed low-nibble-first
    const int qt   = (int)((0x01237654BA98CDEFULL >> ((((u ^ v5) << 2) | s5) * 4)) & 15);
    const int half = (bid >> 7) & 1;
    const int bh   = (v5 << 3) | (bid & 7);
    const size_t base = (size_t)bh * 2048 * 64;
    const unsigned short* Qp = Q + base;
    const unsigned short* Kp = Kg + base;
    const unsigned short* Vp = V + base;
    const int sr  = tid >> 3;
    const int sc8 = tid & 7;
    const int b = bh >> 4, h = bh & 15;

    const int q0 = qt * 128;
    const int lo = half ? (qt + 1) : 0;       // tile range [lo, hi)
    const int hi = half ? (2 * qt + 2) : (qt + 1);
    const int qrow = q0 + wv * 16 + l16;
    const int qtw  = (q0 + wv * 16) >> 6;     // wave's diagonal KV-tile index

    bf16x8 qf[2];
#pragma unroll
    for (int ks = 0; ks < 2; ks++)
        qf[ks] = *(const bf16x8*)(Qp + (size_t)qrow * 64 + ks * 32 + lg * 8);

    float mst = -INFINITY, lsum = 0.f;
    f32x4 oacc[4];
#pragma unroll
    for (int nf = 0; nf < 4; nf++) oacc[nf] = f32x4{0.f, 0.f, 0.f, 0.f};

    uint4 kreg, vreg;
    kreg = *(const uint4*)(Kp + (size_t)(lo * 64 + sr) * 64 + sc8 * 8);
    vreg = *(const uint4*)(Vp + (size_t)(lo * 64 + sr) * 64 + sc8 * 8);

    for (int kt = lo; kt < hi; ++kt) {
        __syncthreads();
        {
            int r = sr;
            *(uint4*)(Kls + r * 64 + ((sc8 ^ (r & 7)) << 3)) = kreg;
            const unsigned short* pv = (const unsigned short*)&vreg;
#pragma unroll
            for (int j = 0; j < 8; j++) {
                int d = sc8 * 8 + j;
                Vt[d * 64 + (r ^ ((j ^ sc8) << 3))] = pv[j];
            }
        }
        __syncthreads();
        if (kt + 1 < hi) {
            kreg = *(const uint4*)(Kp + (size_t)((kt + 1) * 64 + sr) * 64 + sc8 * 8);
            vreg = *(const uint4*)(Vp + (size_t)((kt + 1) * 64 + sr) * 64 + sc8 * 8);
        }

        if (kt > qtw) continue;   // fully masked for this wave

        f32x4 sacc[4];
#pragma unroll
        for (int nf = 0; nf < 4; nf++) sacc[nf] = f32x4{0.f, 0.f, 0.f, 0.f};
#pragma unroll
        for (int ks = 0; ks < 2; ks++) {
            const int koff = ks * 32 + lg * 8;
            bf16x8 kf[4];
#pragma unroll
            for (int nf = 0; nf < 4; nf++) {
                int key = nf * 16 + l16;
                kf[nf] = *(const bf16x8*)(Kls + key * 64 + (koff ^ ((key & 7) << 3)));
            }
#pragma unroll
            for (int nf = 0; nf < 4; nf++)
                sacc[nf] = __builtin_amdgcn_mfma_f32_16x16x32_bf16(kf[nf], qf[ks], sacc[nf], 0, 0, 0);
        }

        if (kt == qtw) {
#pragma unroll
            for (int nf = 0; nf < 4; nf++) {
                int keyb = kt * 64 + nf * 16 + (lg << 2);
#pragma unroll
                for (int j = 0; j < 4; j++)
                    if (keyb + j > qrow) sacc[nf][j] = -INFINITY;
            }
        }

        float xm[4];
#pragma unroll
        for (int nf = 0; nf < 4; nf++)
            xm[nf] = fmaxf(fmaxf(sacc[nf][0], sacc[nf][1]), fmaxf(sacc[nf][2], sacc[nf][3]));
        float x = fmaxf(fmaxf(xm[0], xm[1]), fmaxf(xm[2], xm[3]));
        x = fmaxf(x, __shfl_xor(x, 16));
        x = fmaxf(x, __shfl_xor(x, 32));
        if (!__all(x - mst <= 8.0f)) {   // T13 defer-max
            float mnew  = fmaxf(mst, x);
            float alpha = __builtin_amdgcn_exp2f(mst - mnew);
            mst = mnew;
            lsum *= alpha;
#pragma unroll
            for (int nf = 0; nf < 4; nf++)
#pragma unroll
                for (int j = 0; j < 4; j++) oacc[nf][j] *= alpha;
        }
        float ps[4];
#pragma unroll
        for (int nf = 0; nf < 4; nf++) {
#pragma unroll
            for (int j = 0; j < 4; j++)
                sacc[nf][j] = __builtin_amdgcn_exp2f(sacc[nf][j] - mst);
            ps[nf] = (sacc[nf][0] + sacc[nf][1]) + (sacc[nf][2] + sacc[nf][3]);
        }
        float rs = (ps[0] + ps[1]) + (ps[2] + ps[3]);
        rs += __shfl_xor(rs, 16);
        rs += __shfl_xor(rs, 32);
        lsum += rs;

#pragma unroll
        for (int nf = 0; nf < 4; nf++) {
            bf16x4 pk;
#pragma unroll
            for (int j = 0; j < 4; j++) pk[j] = (__bf16)sacc[nf][j];
            int keyb = nf * 16 + (lg << 2);
            *(bf16x4*)(&Pls[wv][l16 * 64 + (keyb ^ ((l16 & 7) << 3))]) = pk;
        }

#pragma unroll
        for (int ks = 0; ks < 2; ks++) {
            const int koff = ks * 32 + lg * 8;
            bf16x8 pf = *(const bf16x8*)(&Pls[wv][l16 * 64 + (koff ^ ((l16 & 7) << 3))]);
            bf16x8 vf[4];
#pragma unroll
            for (int nf = 0; nf < 4; nf++) {
                int d = nf * 16 + l16;
                vf[nf] = *(const bf16x8*)(Vt + d * 64 + (koff ^ (((d & 7) ^ ((d >> 3) & 7)) << 3)));
            }
#pragma unroll
            for (int nf = 0; nf < 4; nf++)
                oacc[nf] = __builtin_amdgcn_mfma_f32_16x16x32_bf16(vf[nf], pf, oacc[nf], 0, 0, 0);
        }
    }

    // epilogue: UNNORMALIZED O~ + stats (combine divides)
    {
        unsigned short* Op = half ? O2 : O1;
        unsigned short* orow = Op + ((size_t)(b * 2048 + qrow)) * 1024 + h * 64;
#pragma unroll
        for (int nf = 0; nf < 4; nf++) {
            bf16x4 ov;
#pragma unroll
            for (int j = 0; j < 4; j++) ov[j] = (__bf16)oacc[nf][j];
            *(bf16x4*)(orow + nf * 16 + (lg << 2)) = ov;
        }
        if (lg == 0) {
            float2* st = half ? st2 : st1;
            st[bh * 2048 + qrow] = make_float2(mst, lsum);
        }
    }
}

// ---------- combine: O = (a1*O1~ + a2*O2~) / (a1*l1 + a2*l2), in-place into O1 ----------
__global__ void combine(unsigned short* __restrict__ O1,
                        const unsigned short* __restrict__ O2,
                        const float2* __restrict__ st1,
                        const float2* __restrict__ st2) {
    int idx = blockIdx.x * 256 + threadIdx.x;    // 524288 chunks of 8 bf16
    int f = idx * 8;
    int h = (f & 1023) >> 6;
    int t = (f >> 10) & 2047;
    int b = f >> 21;
    int srow = ((b << 4) + h) * 2048 + t;
    float2 s1 = st1[srow], s2 = st2[srow];
    float m = fmaxf(s1.x, s2.x);
    float a1 = __builtin_amdgcn_exp2f(s1.x - m);
    float a2 = __builtin_amdgcn_exp2f(s2.x - m);
    float inv = 1.f / (a1 * s1.y + a2 * s2.y);
    a1 *= inv; a2 *= inv;
    uint4 u1 = *(const uint4*)(O1 + f);
    uint4 u2 = *(const uint4*)(O2 + f);
    const unsigned short* p1 = (const unsigned short*)&u1;
    const unsigned short* p2 = (const unsigned short*)&u2;
    bf16x8 outv;
#pragma unroll
    for (int j = 0; j < 8; j++)
        outv[j] = (__bf16)(a1 * bf2f(p1[j]) + a2 * bf2f(p2[j]));
    *(bf16x8*)(O1 + f) = outv;
}

// ---------- launch ----------
extern "C" void kernel_launch(void* const* d_in, const int* in_sizes, int n_in,
                              void* d_out, int out_size, void* d_ws, size_t ws_size,
                              hipStream_t stream) {
    const float* x     = (const float*)d_in[0];
    const float* wqkv  = (const float*)d_in[1];
    const float* wproj = (const float*)d_in[2];
    float* out = (float*)d_out;

    const int BT = 4096;          // B*T
    const int DIM = 1024;
    const int NQKV = 3072;

    unsigned short* ws = (unsigned short*)d_ws;
    unsigned short* xb     = ws;
    unsigned short* wqkvb  = xb + (size_t)BT * DIM;
    unsigned short* wprojb = wqkvb + (size_t)NQKV * DIM;
    unsigned short* qb     = wprojb + (size_t)DIM * DIM;
    unsigned short* kb     = qb + (size_t)BT * DIM;
    unsigned short* vb     = kb + (size_t)BT * DIM;
    unsigned short* attb   = xb;                          // O1 partial, then final O

    // d_out (16MB fp32) as pre-gemm2 scratch: O2 partial (8MB) + stats (1MB)
    unsigned short* o2  = (unsigned short*)d_out;
    float2* st1 = (float2*)((char*)d_out + 8u * 1024 * 1024);
    float2* st2 = st1 + 65536;

    cvt_all<<<(XN + WQN + WPN) / 4 / 256, 256, 0, stream>>>(x, wqkv, wproj, xb, wqkvb, wprojb);

    gemm_bt<0><<<dim3(NQKV / BN, BT / BM), 256, 0, stream>>>(xb, wqkvb, BT, NQKV, DIM,
                                                             nullptr, qb, kb, vb);

    attn_split<<<1024, 512, 0, stream>>>(qb, kb, vb, attb, o2, st1, st2);
    combine<<<2048, 256, 0, stream>>>(attb, o2, st1, st2);

    gemm_bt<1><<<dim3(DIM / BN, BT / BM), 256, 0, stream>>>(attb, wprojb, BT, DIM, DIM,
                                                            out, nullptr, nullptr, nullptr);
}

// Round 19
// 111.996 us; speedup vs baseline: 1.1143x; 1.1143x over previous
//
#include <hip/hip_runtime.h>
#include <hip/hip_bf16.h>
#include <stdint.h>

// ---------- types ----------
typedef __bf16 bf16x8 __attribute__((ext_vector_type(8)));
typedef __bf16 bf16x4 __attribute__((ext_vector_type(4)));
typedef float  f32x4  __attribute__((ext_vector_type(4)));

__device__ __forceinline__ unsigned short f2bf(float f) {
    unsigned u = __builtin_bit_cast(unsigned, f);
    u += 0x7fffu + ((u >> 16) & 1u);   // RNE
    return (unsigned short)(u >> 16);
}

__device__ __forceinline__ float bf2f(unsigned short u) {
    return __builtin_bit_cast(float, (unsigned)u << 16);
}

__device__ __forceinline__ void gload16(const void* g, void* l) {
    __builtin_amdgcn_global_load_lds((const __attribute__((address_space(1))) void*)g,
                                     (__attribute__((address_space(3))) void*)l, 16, 0, 0);
}

// ---------- fused fp32 -> bf16 convert for x, w_qkv, w_proj (one launch) ----------
#define XN  4194304   // 4096*1024
#define WQN 3145728   // 3072*1024
#define WPN 1048576   // 1024*1024
__global__ void cvt_all(const float* __restrict__ x, const float* __restrict__ wq,
                        const float* __restrict__ wp,
                        unsigned short* __restrict__ xb, unsigned short* __restrict__ wqb,
                        unsigned short* __restrict__ wpb) {
    int i = (blockIdx.x * blockDim.x + threadIdx.x) * 4;
    const float* src; unsigned short* dst; int off;
    if (i < XN)            { src = x;  dst = xb;  off = i; }
    else if (i < XN + WQN) { src = wq; dst = wqb; off = i - XN; }
    else                   { src = wp; dst = wpb; off = i - XN - WQN; }
    float4 v = *(const float4*)(src + off);
    ushort4 o;
    o.x = f2bf(v.x); o.y = f2bf(v.y); o.z = f2bf(v.z); o.w = f2bf(v.w);
    *(ushort4*)(dst + off) = o;
}

// ---------- GEMM C = A * B^T (proven 128x128 structure) ----------
#define BM 128
#define BN 128
#define BKK 64

template<int MODE>
__global__ void gemm_bt(const unsigned short* __restrict__ A,
                        const unsigned short* __restrict__ Bm,
                        int M, int N, int K,
                        float* __restrict__ Cf,
                        unsigned short* __restrict__ Qo,
                        unsigned short* __restrict__ Ko,
                        unsigned short* __restrict__ Vo) {
    __shared__ __align__(16) unsigned short Als[BM * BKK];
    __shared__ __align__(16) unsigned short Bls[BN * BKK];

    const int tid  = threadIdx.x;
    const int lane = tid & 63;
    const int wave = tid >> 6;
    const int wm = wave >> 1, wn = wave & 1;
    const int nwg = gridDim.x * gridDim.y;
    const int lid = blockIdx.y * gridDim.x + blockIdx.x;
    const int cpx = nwg >> 3;
    const int swz = (lid & 7) * cpx + (lid >> 3);
    const int m0 = (swz / gridDim.x) * BM, n0 = (swz % gridDim.x) * BN;
    const int l16 = lane & 15, lg = lane >> 4;

    f32x4 acc[4][4];
#pragma unroll
    for (int i = 0; i < 4; i++)
#pragma unroll
        for (int j = 0; j < 4; j++) acc[i][j] = f32x4{0.f, 0.f, 0.f, 0.f};

    const int r0 = tid >> 3;
    const int c8 = tid & 7;

    for (int k0 = 0; k0 < K; k0 += BKK) {
        __syncthreads();
#pragma unroll
        for (int i = 0; i < 4; i++) {
            gload16(A  + (size_t)(m0 + r0 + i * 32) * K + k0 + c8 * 8,
                    Als + i * 2048 + wave * 512);
            gload16(Bm + (size_t)(n0 + r0 + i * 32) * K + k0 + c8 * 8,
                    Bls + i * 2048 + wave * 512);
        }
        __syncthreads();
#pragma unroll
        for (int ks = 0; ks < 2; ++ks) {
            const int koff = ks * 32 + lg * 8;
            bf16x8 af[4], bfv[4];
#pragma unroll
            for (int mf = 0; mf < 4; ++mf)
                af[mf] = *(const bf16x8*)(Als + (wm * 64 + mf * 16 + l16) * BKK + koff);
#pragma unroll
            for (int nf = 0; nf < 4; ++nf)
                bfv[nf] = *(const bf16x8*)(Bls + (wn * 64 + nf * 16 + l16) * BKK + koff);
#pragma unroll
            for (int mf = 0; mf < 4; ++mf)
#pragma unroll
                for (int nf = 0; nf < 4; ++nf)
                    acc[mf][nf] = __builtin_amdgcn_mfma_f32_16x16x32_bf16(af[mf], bfv[nf], acc[mf][nf], 0, 0, 0);
        }
    }

#pragma unroll
    for (int mf = 0; mf < 4; ++mf) {
        int gm = m0 + wm * 64 + mf * 16 + (lg << 2);
#pragma unroll
        for (int nf = 0; nf < 4; ++nf) {
            int gn = n0 + wn * 64 + nf * 16 + l16;
            if (MODE == 0) {
                int which = gn >> 10;
                int rem = gn & 1023;
                int h = rem >> 6, d = rem & 63;
                unsigned short* dst = (which == 0) ? Qo : (which == 1) ? Ko : Vo;
                float s = (which == 0) ? 0.180336884f : 1.0f;   // 0.125 * log2(e) for Q
#pragma unroll
                for (int j = 0; j < 4; j++) {
                    int m = gm + j;
                    int b = m >> 11, t = m & 2047;
                    dst[((size_t)((b << 4) + h) * 2048 + t) * 64 + d] = f2bf(acc[mf][nf][j] * s);
                }
            } else {
#pragma unroll
                for (int j = 0; j < 4; j++)
                    Cf[(size_t)(gm + j) * N + gn] = acc[mf][nf][j];
            }
        }
    }
}

// ---------- causal flash attention with K-SPLIT (R7 pipeline, 2x TLP) ----------
// 1024 blocks: qt = 15-(bid>>6), half = (bid>>5)&1, bh = bid&31 — LPT order (longest
// first); the dispatcher backfills dynamically (R18 evidence), so launch ORDER is the
// balance lever, not static co-residency maps (R17/R18 both refuted).
// Each half-block stores unnormalized O~ (bf16) + per-row (m,l); combine merges.
// NOTE (R15): no device-scope fence fusion — __threadfence() = L2 writeback on
// multi-XCD CDNA (9x regression). Separate combine kernel is the cheap barrier.
__global__ __launch_bounds__(512, 4)
void attn_split(const unsigned short* __restrict__ Q,
                const unsigned short* __restrict__ Kg,
                const unsigned short* __restrict__ V,
                unsigned short* __restrict__ O1,
                unsigned short* __restrict__ O2,
                float2* __restrict__ st1,
                float2* __restrict__ st2) {
    __shared__ __align__(16) unsigned short Kls[64 * 64];
    __shared__ __align__(16) unsigned short Vt[64 * 64];   // [dim][key], swizzled
    __shared__ __align__(16) unsigned short Pls[8][16 * 64];

    const int tid = threadIdx.x, lane = tid & 63, wv = tid >> 6;
    const int l16 = lane & 15, lg = lane >> 4;
    const int bid = blockIdx.x;
    const int qt   = 15 - (bid >> 6);         // q-tile (128 rows), longest first
    const int half = (bid >> 5) & 1;
    const int bh   = bid & 31;
    const size_t base = (size_t)bh * 2048 * 64;
    const unsigned short* Qp = Q + base;
    const unsigned short* Kp = Kg + base;
    const unsigned short* Vp = V + base;
    const int sr  = tid >> 3;
    const int sc8 = tid & 7;
    const int b = bh >> 4, h = bh & 15;

    const int q0 = qt * 128;
    const int lo = half ? (qt + 1) : 0;       // tile range [lo, hi)
    const int hi = half ? (2 * qt + 2) : (qt + 1);
    const int qrow = q0 + wv * 16 + l16;
    const int qtw  = (q0 + wv * 16) >> 6;     // wave's diagonal KV-tile index

    bf16x8 qf[2];
#pragma unroll
    for (int ks = 0; ks < 2; ks++)
        qf[ks] = *(const bf16x8*)(Qp + (size_t)qrow * 64 + ks * 32 + lg * 8);

    float mst = -INFINITY, lsum = 0.f;
    f32x4 oacc[4];
#pragma unroll
    for (int nf = 0; nf < 4; nf++) oacc[nf] = f32x4{0.f, 0.f, 0.f, 0.f};

    uint4 kreg, vreg;
    kreg = *(const uint4*)(Kp + (size_t)(lo * 64 + sr) * 64 + sc8 * 8);
    vreg = *(const uint4*)(Vp + (size_t)(lo * 64 + sr) * 64 + sc8 * 8);

    for (int kt = lo; kt < hi; ++kt) {
        __syncthreads();
        {
            int r = sr;
            *(uint4*)(Kls + r * 64 + ((sc8 ^ (r & 7)) << 3)) = kreg;
            const unsigned short* pv = (const unsigned short*)&vreg;
#pragma unroll
            for (int j = 0; j < 8; j++) {
                int d = sc8 * 8 + j;
                Vt[d * 64 + (r ^ ((j ^ sc8) << 3))] = pv[j];
            }
        }
        __syncthreads();
        if (kt + 1 < hi) {
            kreg = *(const uint4*)(Kp + (size_t)((kt + 1) * 64 + sr) * 64 + sc8 * 8);
            vreg = *(const uint4*)(Vp + (size_t)((kt + 1) * 64 + sr) * 64 + sc8 * 8);
        }

        if (kt > qtw) continue;   // fully masked for this wave

        f32x4 sacc[4];
#pragma unroll
        for (int nf = 0; nf < 4; nf++) sacc[nf] = f32x4{0.f, 0.f, 0.f, 0.f};
#pragma unroll
        for (int ks = 0; ks < 2; ks++) {
            const int koff = ks * 32 + lg * 8;
            bf16x8 kf[4];
#pragma unroll
            for (int nf = 0; nf < 4; nf++) {
                int key = nf * 16 + l16;
                kf[nf] = *(const bf16x8*)(Kls + key * 64 + (koff ^ ((key & 7) << 3)));
            }
#pragma unroll
            for (int nf = 0; nf < 4; nf++)
                sacc[nf] = __builtin_amdgcn_mfma_f32_16x16x32_bf16(kf[nf], qf[ks], sacc[nf], 0, 0, 0);
        }

        if (kt == qtw) {
#pragma unroll
            for (int nf = 0; nf < 4; nf++) {
                int keyb = kt * 64 + nf * 16 + (lg << 2);
#pragma unroll
                for (int j = 0; j < 4; j++)
                    if (keyb + j > qrow) sacc[nf][j] = -INFINITY;
            }
        }

        float xm[4];
#pragma unroll
        for (int nf = 0; nf < 4; nf++)
            xm[nf] = fmaxf(fmaxf(sacc[nf][0], sacc[nf][1]), fmaxf(sacc[nf][2], sacc[nf][3]));
        float x = fmaxf(fmaxf(xm[0], xm[1]), fmaxf(xm[2], xm[3]));
        x = fmaxf(x, __shfl_xor(x, 16));
        x = fmaxf(x, __shfl_xor(x, 32));
        if (!__all(x - mst <= 8.0f)) {   // T13 defer-max
            float mnew  = fmaxf(mst, x);
            float alpha = __builtin_amdgcn_exp2f(mst - mnew);
            mst = mnew;
            lsum *= alpha;
#pragma unroll
            for (int nf = 0; nf < 4; nf++)
#pragma unroll
                for (int j = 0; j < 4; j++) oacc[nf][j] *= alpha;
        }
        float ps[4];
#pragma unroll
        for (int nf = 0; nf < 4; nf++) {
#pragma unroll
            for (int j = 0; j < 4; j++)
                sacc[nf][j] = __builtin_amdgcn_exp2f(sacc[nf][j] - mst);
            ps[nf] = (sacc[nf][0] + sacc[nf][1]) + (sacc[nf][2] + sacc[nf][3]);
        }
        float rs = (ps[0] + ps[1]) + (ps[2] + ps[3]);
        rs += __shfl_xor(rs, 16);
        rs += __shfl_xor(rs, 32);
        lsum += rs;

#pragma unroll
        for (int nf = 0; nf < 4; nf++) {
            bf16x4 pk;
#pragma unroll
            for (int j = 0; j < 4; j++) pk[j] = (__bf16)sacc[nf][j];
            int keyb = nf * 16 + (lg << 2);
            *(bf16x4*)(&Pls[wv][l16 * 64 + (keyb ^ ((l16 & 7) << 3))]) = pk;
        }

#pragma unroll
        for (int ks = 0; ks < 2; ks++) {
            const int koff = ks * 32 + lg * 8;
            bf16x8 pf = *(const bf16x8*)(&Pls[wv][l16 * 64 + (koff ^ ((l16 & 7) << 3))]);
            bf16x8 vf[4];
#pragma unroll
            for (int nf = 0; nf < 4; nf++) {
                int d = nf * 16 + l16;
                vf[nf] = *(const bf16x8*)(Vt + d * 64 + (koff ^ (((d & 7) ^ ((d >> 3) & 7)) << 3)));
            }
#pragma unroll
            for (int nf = 0; nf < 4; nf++)
                oacc[nf] = __builtin_amdgcn_mfma_f32_16x16x32_bf16(vf[nf], pf, oacc[nf], 0, 0, 0);
        }
    }

    // epilogue: UNNORMALIZED O~ + stats (combine divides)
    {
        unsigned short* Op = half ? O2 : O1;
        unsigned short* orow = Op + ((size_t)(b * 2048 + qrow)) * 1024 + h * 64;
#pragma unroll
        for (int nf = 0; nf < 4; nf++) {
            bf16x4 ov;
#pragma unroll
            for (int j = 0; j < 4; j++) ov[j] = (__bf16)oacc[nf][j];
            *(bf16x4*)(orow + nf * 16 + (lg << 2)) = ov;
        }
        if (lg == 0) {
            float2* st = half ? st2 : st1;
            st[bh * 2048 + qrow] = make_float2(mst, lsum);
        }
    }
}

// ---------- combine: O = (a1*O1~ + a2*O2~) / (a1*l1 + a2*l2), in-place into O1 ----------
__global__ void combine(unsigned short* __restrict__ O1,
                        const unsigned short* __restrict__ O2,
                        const float2* __restrict__ st1,
                        const float2* __restrict__ st2) {
    int idx = blockIdx.x * 256 + threadIdx.x;    // 524288 chunks of 8 bf16
    int f = idx * 8;
    int h = (f & 1023) >> 6;
    int t = (f >> 10) & 2047;
    int b = f >> 21;
    int srow = ((b << 4) + h) * 2048 + t;
    float2 s1 = st1[srow], s2 = st2[srow];
    float m = fmaxf(s1.x, s2.x);
    float a1 = __builtin_amdgcn_exp2f(s1.x - m);
    float a2 = __builtin_amdgcn_exp2f(s2.x - m);
    float inv = 1.f / (a1 * s1.y + a2 * s2.y);
    a1 *= inv; a2 *= inv;
    uint4 u1 = *(const uint4*)(O1 + f);
    uint4 u2 = *(const uint4*)(O2 + f);
    const unsigned short* p1 = (const unsigned short*)&u1;
    const unsigned short* p2 = (const unsigned short*)&u2;
    bf16x8 outv;
#pragma unroll
    for (int j = 0; j < 8; j++)
        outv[j] = (__bf16)(a1 * bf2f(p1[j]) + a2 * bf2f(p2[j]));
    *(bf16x8*)(O1 + f) = outv;
}

// ---------- launch ----------
extern "C" void kernel_launch(void* const* d_in, const int* in_sizes, int n_in,
                              void* d_out, int out_size, void* d_ws, size_t ws_size,
                              hipStream_t stream) {
    const float* x     = (const float*)d_in[0];
    const float* wqkv  = (const float*)d_in[1];
    const float* wproj = (const float*)d_in[2];
    float* out = (float*)d_out;

    const int BT = 4096;          // B*T
    const int DIM = 1024;
    const int NQKV = 3072;

    unsigned short* ws = (unsigned short*)d_ws;
    unsigned short* xb     = ws;
    unsigned short* wqkvb  = xb + (size_t)BT * DIM;
    unsigned short* wprojb = wqkvb + (size_t)NQKV * DIM;
    unsigned short* qb     = wprojb + (size_t)DIM * DIM;
    unsigned short* kb     = qb + (size_t)BT * DIM;
    unsigned short* vb     = kb + (size_t)BT * DIM;
    unsigned short* attb   = xb;                          // O1 partial, then final O

    // d_out (16MB fp32) as pre-gemm2 scratch: O2 partial (8MB) + stats (1MB)
    unsigned short* o2  = (unsigned short*)d_out;
    float2* st1 = (float2*)((char*)d_out + 8u * 1024 * 1024);
    float2* st2 = st1 + 65536;

    cvt_all<<<(XN + WQN + WPN) / 4 / 256, 256, 0, stream>>>(x, wqkv, wproj, xb, wqkvb, wprojb);

    gemm_bt<0><<<dim3(NQKV / BN, BT / BM), 256, 0, stream>>>(xb, wqkvb, BT, NQKV, DIM,
                                                             nullptr, qb, kb, vb);

    attn_split<<<1024, 512, 0, stream>>>(qb, kb, vb, attb, o2, st1, st2);
    combine<<<2048, 256, 0, stream>>>(attb, o2, st1, st2);

    gemm_bt<1><<<dim3(DIM / BN, BT / BM), 256, 0, stream>>>(attb, wprojb, BT, DIM, DIM,
                                                            out, nullptr, nullptr, nullptr);
}